// Round 9
// baseline (121.758 us; speedup 1.0000x reference)
//
#include <hip/hip_runtime.h>
#include <hip/hip_bf16.h>

// SoftmaxLossRScore: mean(relu(logsumexp(A @ Neg^T, axis=1) - rowdot(A,P) + r + 1))
// B=2048, N=32768, D=128. bf16 MFMA fused GEMM+sumexp, no [B,N] materialization.
// A pre-scaled by log2(e) so epilogue is a bare v_exp_f32 (exp2).
// R10: OPERAND SWAP. Prior structure streamed B (8MB) with 16-block sharing
//     scattered over 8 XCDs -> staging loads were L2 misses (FETCH=4x B);
//     schedule levers (R6 depth, R9 phases, R8 traffic, R7 occupancy) all
//     neutral because the stall is SOURCE latency. Now: each block owns a
//     64-col N-slice; B-frags loaded ONCE straight to registers; streams all
//     of A (512KB total -> resident in EVERY XCD L2 after first touch;
//     staging = ~200cy L2 hits). B read exactly once chip-wide. Swapped
//     MFMA mfma(bf,af,acc) puts A-rows on the lane index -> in-lane col-sum
//     + 2 shuffles; per-tile row partials stored non-atomically to
//     partial[1024][2048]; finalizeA reduces (coalesced).
// R10b: hardened after container failure -- static LDS capped at 64 KB
//     (2x32KB A dbuf only; B-slice register-direct, no B LDS).

#define B_ROWS 2048
#define N_NEG  32768
#define DIM    128
#define LOG2E  1.4426950408889634f
#define LN2    0.6931471805599453f
#define TSTEPS 16            // A-tiles of 128 rows

typedef __bf16 bf16x8 __attribute__((ext_vector_type(8)));
typedef float  f32x4  __attribute__((ext_vector_type(4)));

static __device__ inline unsigned short f2bf(float f) {
    union { float f; unsigned u; } v; v.f = f;
    unsigned r = v.u + 0x7FFF + ((v.u >> 16) & 1);   // round-to-nearest-even
    return (unsigned short)(r >> 16);
}

static __device__ inline void load_lds16(const void* g, void* s) {
    __builtin_amdgcn_global_load_lds(
        (const __attribute__((address_space(1))) void*)g,
        (__attribute__((address_space(3))) void*)s,
        16, 0, 0);
}

// ---------- P1 (merged): anchor->bf16*log2e + pos_sim + zero sumexp, neg->bf16
__global__ void prep(const float* __restrict__ anchor,
                     const float* __restrict__ positive,
                     const float* __restrict__ neg,
                     unsigned short* __restrict__ a_bf,
                     unsigned short* __restrict__ n_bf,
                     float* __restrict__ pos_sim,
                     float* __restrict__ sumexp) {
    int t = threadIdx.x;
    if (blockIdx.x < 256) {
        int row = blockIdx.x * 8 + (t >> 5);
        int c4  = (t & 31) * 4;
        const float4 a4 = *(const float4*)(anchor   + row * DIM + c4);
        const float4 p4 = *(const float4*)(positive + row * DIM + c4);
        float dot = a4.x * p4.x + a4.y * p4.y + a4.z * p4.z + a4.w * p4.w;
        ushort4 ab;
        ab.x = f2bf(a4.x * LOG2E); ab.y = f2bf(a4.y * LOG2E);
        ab.z = f2bf(a4.z * LOG2E); ab.w = f2bf(a4.w * LOG2E);
        *(ushort4*)(a_bf + row * DIM + c4) = ab;
        #pragma unroll
        for (int m = 1; m <= 16; m <<= 1) dot += __shfl_xor(dot, m, 64);
        if ((t & 31) == 0) { pos_sim[row] = dot; sumexp[row] = 0.0f; }
    } else {
        int i = (blockIdx.x - 256) * 256 + t;   // float4 index
        #pragma unroll
        for (int k = 0; k < 4; k++) {
            int idx = i + k * (1024 * 256);
            float4 v = *(const float4*)(neg + (size_t)idx * 4);
            ushort4 o;
            o.x = f2bf(v.x); o.y = f2bf(v.y); o.z = f2bf(v.z); o.w = f2bf(v.w);
            *(ushort4*)(n_bf + (size_t)idx * 4) = o;
        }
    }
}

// ---------- main: fused bf16 GEMM + sum(exp2), A-streamed / B-resident ------
// Grid 512 blocks (natural order) = 512 N-slices of 64 cols. Block 256 thr =
// 4 waves (2 row x 2 col): wave rows = wr*64 within each 128-row A-tile, wave
// cols = wc*32 (2 j-subtiles of 16). B-frags loaded once, register-resident
// (bf[2][4]; straight from global, standard fragment layout, no swizzle).
// A-tiles (128 rows, 32 KB) double-buffered in LDS (64 KB total), staged 2
// ahead, counted vmcnt(8): per wave per tile 8 A-loads + 4 partial-stores;
// at loop top the oldest 12 (A(t) + stores) drain, A(t+1)'s 8 stay in flight.
// LDS rows are 256B; 16B chunk j of row r holds global chunk j^(r&7)
// (swizzle on the global source address; DMA dest stays linear).
__global__ __launch_bounds__(256, 2) void fused_gemm_lse(
        const unsigned short* __restrict__ A,
        const unsigned short* __restrict__ Nb,
        float* __restrict__ partial) {
    __shared__ unsigned short lds[2 * 16384];   // 64 KB: Abuf0 | Abuf1

    const int chunk = blockIdx.x;              // 64-col slice id
    const int wave = threadIdx.x >> 6, lane = threadIdx.x & 63;
    const int wr = wave >> 1, wc = wave & 1;
    const int q = lane >> 4, c = lane & 15;
    const int lrow = lane >> 4;       // staging: row within 4-row group
    const int lchk = lane & 15;       // staging: 16B chunk within row

    const unsigned short* Ag = A;
    const unsigned short* Bg = Nb + (size_t)chunk * 64 * DIM;

// stage A-tile tt (128 rows) into buffer bsel (8 loads/wave; wave w covers
// rows w*32..+31). Global source per-lane with XOR swizzle; LDS dest linear.
#define STAGE_A(tt, bsel)                                                      \
    {                                                                          \
        const unsigned short* Gt_ = Ag + (size_t)(tt) * 128 * DIM;             \
        _Pragma("unroll")                                                      \
        for (int i_ = 0; i_ < 8; i_++) {                                       \
            int rloc_ = wave * 32 + i_ * 4;                                    \
            int rg_   = rloc_ + lrow;                                          \
            int gofs_ = rg_ * DIM + ((lchk ^ (rg_ & 7)) << 3);                 \
            load_lds16(Gt_ + gofs_, &lds[(bsel) * 16384 + rloc_ * DIM]);       \
        }                                                                      \
    }

    // ---- prologue: B-frags -> registers (oldest vmem ops), A0, A1 ----
    bf16x8 bf[2][4];
    #pragma unroll
    for (int j = 0; j < 2; j++) {
        const unsigned short* br = Bg + (size_t)(wc * 32 + j * 16 + c) * DIM;
        #pragma unroll
        for (int k = 0; k < 4; k++)
            bf[j][k] = *(const bf16x8*)(br + (k * 4 + q) * 8);
    }
    STAGE_A(0, 0);
    STAGE_A(1, 1);
    asm volatile("s_waitcnt vmcnt(8)" ::: "memory");   // B+A0 landed; A1 flying
    __builtin_amdgcn_s_barrier();

    // swizzled k-step chunk offsets (ushort units); all fragment rows are
    // == c (mod 8), so this is invariant across t/i.
    int swz[4];
    #pragma unroll
    for (int k = 0; k < 4; k++) swz[k] = (((k * 4 + q) ^ (c & 7)) << 3);

    const f32x4 zero4 = {0.f, 0.f, 0.f, 0.f};
    float* Pp = partial + (size_t)(chunk * 2 + wc) * B_ROWS;

    for (int t = 0; t < TSTEPS; t++) {
        // own A(t) loads + older partial-stores retired; A(t+1) in flight
        if (t < TSTEPS - 1) asm volatile("s_waitcnt vmcnt(8)" ::: "memory");
        else                asm volatile("s_waitcnt vmcnt(0)" ::: "memory");
        __builtin_amdgcn_s_barrier();          // all waves' A(t) visible

        const int ab = (t & 1) * 16384;
        #pragma unroll
        for (int i = 0; i < 4; i++) {          // 4 row-subtiles of wave's 64
            int arow = wr * 64 + i * 16 + c;
            bf16x8 af[4];
            #pragma unroll
            for (int k = 0; k < 4; k++)
                af[k] = *(const bf16x8*)&lds[ab + arow * DIM + swz[k]];
            // swapped operands: D[negcol sub = q*4+reg][Arow = c]
            f32x4 acc0 = __builtin_amdgcn_mfma_f32_16x16x32_bf16(bf[0][0], af[0], zero4, 0, 0, 0);
            f32x4 acc1 = __builtin_amdgcn_mfma_f32_16x16x32_bf16(bf[1][0], af[0], zero4, 0, 0, 0);
            #pragma unroll
            for (int k = 1; k < 4; k++) {
                acc0 = __builtin_amdgcn_mfma_f32_16x16x32_bf16(bf[0][k], af[k], acc0, 0, 0, 0);
                acc1 = __builtin_amdgcn_mfma_f32_16x16x32_bf16(bf[1][k], af[k], acc1, 0, 0, 0);
            }
            float rs = __builtin_amdgcn_exp2f(acc0[0]) + __builtin_amdgcn_exp2f(acc0[1])
                     + __builtin_amdgcn_exp2f(acc0[2]) + __builtin_amdgcn_exp2f(acc0[3])
                     + __builtin_amdgcn_exp2f(acc1[0]) + __builtin_amdgcn_exp2f(acc1[1])
                     + __builtin_amdgcn_exp2f(acc1[2]) + __builtin_amdgcn_exp2f(acc1[3]);
            rs += __shfl_xor(rs, 16, 64);      // combine the 4 q-groups
            rs += __shfl_xor(rs, 32, 64);
            if (lane < 16)                     // 16 consecutive rows, 64B store
                Pp[t * 128 + wr * 64 + i * 16 + lane] = rs;
        }
        asm volatile("s_waitcnt lgkmcnt(0)" ::: "memory");
        __builtin_amdgcn_s_barrier();          // all reads of buf(t&1) done
        if (t + 2 < TSTEPS) STAGE_A(t + 2, t & 1);
    }
#undef STAGE_A
}

// ---------- finalizeA: reduce partial[1024][2048] -> sumexp[2048] -----------
// Grid 64 x 256: block b covers rows (b&7)*256.. and c-slice (b>>3)*128..
__global__ void finalizeA(const float* __restrict__ partial,
                          float* __restrict__ sumexp) {
    int r  = (blockIdx.x & 7) * 256 + threadIdx.x;
    int cb = blockIdx.x >> 3;
    const float* P = partial + (size_t)cb * 128 * B_ROWS + r;
    float a0 = 0.f, a1 = 0.f, a2 = 0.f, a3 = 0.f;
    #pragma unroll 4
    for (int cidx = 0; cidx < 128; cidx += 4) {
        a0 += P[(size_t)(cidx + 0) * B_ROWS];
        a1 += P[(size_t)(cidx + 1) * B_ROWS];
        a2 += P[(size_t)(cidx + 2) * B_ROWS];
        a3 += P[(size_t)(cidx + 3) * B_ROWS];
    }
    atomicAdd(&sumexp[r], (a0 + a1) + (a2 + a3));
}

// ---------- finalizeB: lse, relu, mean -> scalar ----------------------------
__global__ void finalizeB(const float* __restrict__ sumexp,
                          const float* __restrict__ pos_sim,
                          const float* __restrict__ r_score,
                          float* __restrict__ out) {
    __shared__ float red[4];
    int t = threadIdx.x;
    float acc = 0.0f;
    #pragma unroll
    for (int i = 0; i < 8; i++) {
        int row = t + i * 256;
        float lse  = __log2f(sumexp[row]) * LN2;   // A was pre-scaled by log2e
        float loss = lse - pos_sim[row] + r_score[row] + 1.0f;
        acc += fmaxf(loss, 0.0f);
    }
    #pragma unroll
    for (int m = 1; m <= 32; m <<= 1) acc += __shfl_xor(acc, m, 64);
    if ((t & 63) == 0) red[t >> 6] = acc;
    __syncthreads();
    if (t == 0) out[0] = (red[0] + red[1] + red[2] + red[3]) * (1.0f / (float)B_ROWS);
}

extern "C" void kernel_launch(void* const* d_in, const int* in_sizes, int n_in,
                              void* d_out, int out_size, void* d_ws, size_t ws_size,
                              hipStream_t stream) {
    const float* anchor   = (const float*)d_in[0];
    const float* positive = (const float*)d_in[1];
    const float* negative = (const float*)d_in[2];
    const float* r_score  = (const float*)d_in[3];
    float* out = (float*)d_out;

    char* ws = (char*)d_ws;
    float* sumexp           = (float*)ws;                         // 2048 f32
    float* pos_sim          = (float*)(ws + 8192);                // 2048 f32
    float* partial          = (float*)(ws + 16384);               // 8 MB
    unsigned short* a_bf    = (unsigned short*)(ws + 16384 + 8388608);     // 512 KB
    unsigned short* n_bf    = (unsigned short*)(ws + 16384 + 8388608 + 524288); // 8 MB

    prep<<<1280, 256, 0, stream>>>(anchor, positive, negative, a_bf, n_bf, pos_sim, sumexp);
    fused_gemm_lse<<<512, 256, 0, stream>>>(a_bf, n_bf, partial);
    finalizeA<<<64, 256, 0, stream>>>(partial, sumexp);
    finalizeB<<<1, 256, 0, stream>>>(sumexp, pos_sim, r_score, out);
}